// Round 3
// baseline (468.482 us; speedup 1.0000x reference)
//
#include <hip/hip_runtime.h>

typedef unsigned short u16;
typedef unsigned int   u32;
using bf16x8 = __attribute__((ext_vector_type(8))) __bf16;
using f32x4  = __attribute__((ext_vector_type(4))) float;

__device__ __forceinline__ float b2f(u16 u){ union { float f; u32 i; } v; v.i = ((u32)u) << 16; return v.f; }
__device__ __forceinline__ u16 f2b(float f){
  union { float f; u32 i; } v; v.f = f;
  u32 r = v.i + 0x7FFFu + ((v.i >> 16) & 1u);
  return (u16)(r >> 16);
}

// ---------------------------------------------------------------- fp32 -> bf16 weight convert
// grid (1024, 4): blockIdx.y selects which 1024x1024 matrix; 4 elems/thread
__global__ __launch_bounds__(256) void cvt_w(const float* __restrict__ s0, const float* __restrict__ s1,
                                             const float* __restrict__ s2, const float* __restrict__ s3,
                                             u16* __restrict__ d){
  const float* srcs[4] = {s0, s1, s2, s3};
  const float* s = srcs[blockIdx.y];
  u16* dd = d + (size_t)blockIdx.y * (1024u * 1024u);
  const int i = (blockIdx.x * 256 + threadIdx.x) * 4;
  float4 v = *(const float4*)(s + i);
  uint2 o;
  o.x = (u32)f2b(v.x) | ((u32)f2b(v.y) << 16);
  o.y = (u32)f2b(v.z) | ((u32)f2b(v.w) << 16);
  *(uint2*)(dd + i) = o;
}

// ---------------------------------------------------------------- LayerNorm (fp32 in, bf16 out)
__global__ __launch_bounds__(256) void ln_kernel(const float* __restrict__ x, const float* __restrict__ g,
                                                 const float* __restrict__ be, u16* __restrict__ h){
  const int row = blockIdx.x, tid = threadIdx.x;
  const float* xr = x + (size_t)row * 1024u;
  float4 raw = *(const float4*)(xr + tid * 4);
  float s  = raw.x + raw.y + raw.z + raw.w;
  float sq = raw.x*raw.x + raw.y*raw.y + raw.z*raw.z + raw.w*raw.w;
  #pragma unroll
  for (int m = 1; m < 64; m <<= 1){ s += __shfl_xor(s, m); sq += __shfl_xor(sq, m); }
  __shared__ float ws[4], wq[4];
  if ((tid & 63) == 0){ ws[tid >> 6] = s; wq[tid >> 6] = sq; }
  __syncthreads();
  s  = ws[0] + ws[1] + ws[2] + ws[3];
  sq = wq[0] + wq[1] + wq[2] + wq[3];
  const float mu = s * (1.0f / 1024.0f);
  const float rstd = rsqrtf(sq * (1.0f / 1024.0f) - mu * mu + 1e-5f);
  float4 gg = *(const float4*)(g + tid * 4);
  float4 bb = *(const float4*)(be + tid * 4);
  float y0 = (raw.x - mu) * rstd * gg.x + bb.x;
  float y1 = (raw.y - mu) * rstd * gg.y + bb.y;
  float y2 = (raw.z - mu) * rstd * gg.z + bb.z;
  float y3 = (raw.w - mu) * rstd * gg.w + bb.w;
  uint2 outv;
  outv.x = (u32)f2b(y0) | ((u32)f2b(y1) << 16);
  outv.y = (u32)f2b(y2) | ((u32)f2b(y3) << 16);
  *(uint2*)(h + (size_t)row * 1024u + tid * 4) = outv;
}

// ---------------------------------------------------------------- GEMM: C = A * W^T + bias (+res)
// A: MxK bf16 row-major, W: NxK bf16 (pre-converted), bias/res fp32.
// F32OUT=1: store fp32; else store bf16.
// 128x128 tile, BK=32, 4 waves (2x2 of 64x64), mfma 16x16x32 bf16
template<int F32OUT>
__global__ __launch_bounds__(256) void gemm_bt(const u16* __restrict__ A, const u16* __restrict__ W,
                                               const float* __restrict__ bias, const float* __restrict__ res,
                                               void* __restrict__ Cv, int M, int N, int K){
  __shared__ u16 lA[128 * 32];
  __shared__ u16 lB[128 * 32];
  const int tid = threadIdx.x;
  const int lane = tid & 63, wv = tid >> 6, l15 = lane & 15, quad = lane >> 4;
  const int wr = wv >> 1, wc = wv & 1;
  const int row0 = blockIdx.x * 128, col0 = blockIdx.y * 128;
  f32x4 acc[4][4] = {};
  const int nkt = K >> 5;
  for (int kt = 0; kt < nkt; ++kt){
    __syncthreads();
    #pragma unroll
    for (int jj = 0; jj < 2; ++jj){
      int idx = jj * 256 + tid;
      int r = idx >> 2, c = idx & 3;          // 128 rows x 4 chunks of 8 bf16
      *(uint4*)&lA[idx * 8] = *(const uint4*)(A + (size_t)(row0 + r) * K + (kt * 32 + c * 8));
      *(uint4*)&lB[idx * 8] = *(const uint4*)(W + (size_t)(col0 + r) * K + (kt * 32 + c * 8));
    }
    __syncthreads();
    bf16x8 af[4], bf[4];
    #pragma unroll
    for (int i = 0; i < 4; ++i) af[i] = *(const bf16x8*)&lA[(wr * 64 + i * 16 + l15) * 32 + quad * 8];
    #pragma unroll
    for (int j = 0; j < 4; ++j) bf[j] = *(const bf16x8*)&lB[(wc * 64 + j * 16 + l15) * 32 + quad * 8];
    #pragma unroll
    for (int i = 0; i < 4; ++i)
      #pragma unroll
      for (int j = 0; j < 4; ++j)
        acc[i][j] = __builtin_amdgcn_mfma_f32_16x16x32_bf16(af[i], bf[j], acc[i][j], 0, 0, 0);
  }
  #pragma unroll
  for (int i = 0; i < 4; ++i){
    const int grow = row0 + wr * 64 + i * 16 + quad * 4;
    #pragma unroll
    for (int j = 0; j < 4; ++j){
      const int gcol = col0 + wc * 64 + j * 16 + l15;
      const float bb = bias[gcol];
      #pragma unroll
      for (int r = 0; r < 4; ++r){
        size_t off = (size_t)(grow + r) * N + gcol;
        float v = acc[i][j][r] + bb;
        if (res) v += res[off];
        if (F32OUT) ((float*)Cv)[off] = v;
        else        ((u16*)Cv)[off] = f2b(v);
      }
    }
  }
}

// ---------------------------------------------------------------- V (b,s,h*64+d) -> Vt (b,h,d,s)  [bf16]
__global__ __launch_bounds__(256) void transpose_v(const u16* __restrict__ V, u16* __restrict__ Vt){
  __shared__ u16 t[64 * 66];
  const int bh = blockIdx.x >> 5, st = blockIdx.x & 31;
  const int b = bh >> 4, hh = bh & 15;
  const u16* Vg = V + ((size_t)b * 2048u + st * 64u) * 1024u + hh * 64;
  u16* Og = Vt + (size_t)bh * 64u * 2048u + st * 64u;
  #pragma unroll
  for (int i = 0; i < 16; ++i){
    int idx = i * 256 + threadIdx.x;
    int s = idx >> 6, d = idx & 63;
    t[s * 66 + d] = Vg[(size_t)s * 1024u + d];
  }
  __syncthreads();
  #pragma unroll
  for (int i = 0; i < 16; ++i){
    int idx = i * 256 + threadIdx.x;
    int d = idx >> 6, s = idx & 63;
    Og[(size_t)d * 2048u + s] = t[s * 66 + d];
  }
}

// ---------------------------------------------------------------- flash attention (bf16 in/out)
// grid: (B*NH)*(S/64); block 256 = 4 waves; wave handles 16 q-rows; K/V tiles of 64
// O may alias Q: each block reads only its own 64x64 Q region once at start,
// writes O over that same region at the end. No cross-block access.
#define AS 72   // LDS row stride (elems): 144B = 16B-aligned, odd dword-stride
__global__ __launch_bounds__(256) void attn_kernel(const u16* __restrict__ Q, const u16* __restrict__ K,
                                                   const u16* __restrict__ Vt, u16* __restrict__ O){
  __shared__ u16 kls[64 * AS];
  __shared__ u16 vls[64 * AS];
  __shared__ u16 pls[4 * 16 * AS];
  const int tid = threadIdx.x;
  const int lane = tid & 63, wv = tid >> 6, l15 = lane & 15, quad = lane >> 4;
  const int bh = blockIdx.x >> 5, qt = blockIdx.x & 31;
  const int b = bh >> 4, hh = bh & 15;
  const int q0 = qt * 64;
  const u16* Qg = Q + ((size_t)b * 2048u) * 1024u + hh * 64;
  const u16* Kg = K + ((size_t)b * 2048u) * 1024u + hh * 64;
  const u16* Vg = Vt + (size_t)bh * 64u * 2048u;
  u16* Og = O + ((size_t)b * 2048u) * 1024u + hh * 64;

  // stage Q tile (reuses kls), pull per-wave A-frags into registers
  #pragma unroll
  for (int jj = 0; jj < 2; ++jj){
    int idx = jj * 256 + tid, r = idx >> 3, c = idx & 7;   // 64 rows x 8 chunks
    *(uint4*)&kls[r * AS + c * 8] = *(const uint4*)(Qg + (size_t)(q0 + r) * 1024u + c * 8);
  }
  __syncthreads();
  bf16x8 qf[2];
  #pragma unroll
  for (int kk = 0; kk < 2; ++kk)
    qf[kk] = *(const bf16x8*)&kls[(wv * 16 + l15) * AS + kk * 32 + quad * 8];

  float m_r[4], l_r[4];
  f32x4 o[4] = {};
  #pragma unroll
  for (int r = 0; r < 4; ++r){ m_r[r] = -1.0e30f; l_r[r] = 0.0f; }

  for (int kt = 0; kt < 32; ++kt){
    __syncthreads();
    const int s0 = kt * 64;
    #pragma unroll
    for (int jj = 0; jj < 2; ++jj){
      int idx = jj * 256 + tid, r = idx >> 3, c = idx & 7;
      *(uint4*)&kls[r * AS + c * 8] = *(const uint4*)(Kg + (size_t)(s0 + r) * 1024u + c * 8);
      *(uint4*)&vls[r * AS + c * 8] = *(const uint4*)(Vg + (size_t)r * 2048u + s0 + c * 8);
    }
    __syncthreads();

    // S-tile = Q K^T  (C layout: col=l15 -> s', row=quad*4+reg -> q-row)
    f32x4 sc[4];
    #pragma unroll
    for (int j = 0; j < 4; ++j){
      f32x4 a = {0.f, 0.f, 0.f, 0.f};
      #pragma unroll
      for (int kk = 0; kk < 2; ++kk){
        bf16x8 bfr = *(const bf16x8*)&kls[(j * 16 + l15) * AS + kk * 32 + quad * 8];
        a = __builtin_amdgcn_mfma_f32_16x16x32_bf16(qf[kk], bfr, a, 0, 0, 0);
      }
      sc[j] = a;
    }

    u16* pw = &pls[wv * 16 * AS];
    #pragma unroll
    for (int r = 0; r < 4; ++r){
      #pragma unroll
      for (int j = 0; j < 4; ++j) sc[j][r] *= 0.125f;
      float t = fmaxf(fmaxf(sc[0][r], sc[1][r]), fmaxf(sc[2][r], sc[3][r]));
      #pragma unroll
      for (int mm = 1; mm < 16; mm <<= 1) t = fmaxf(t, __shfl_xor(t, mm));
      const float mn = fmaxf(m_r[r], t);
      const float alpha = __expf(m_r[r] - mn);
      m_r[r] = mn;
      float rs = 0.f;
      #pragma unroll
      for (int j = 0; j < 4; ++j){
        float p = __expf(sc[j][r] - mn);
        sc[j][r] = p;
        rs += p;
      }
      #pragma unroll
      for (int mm = 1; mm < 16; mm <<= 1) rs += __shfl_xor(rs, mm);
      l_r[r] = l_r[r] * alpha + rs;
      #pragma unroll
      for (int j = 0; j < 4; ++j) o[j][r] *= alpha;
      #pragma unroll
      for (int j = 0; j < 4; ++j) pw[(quad * 4 + r) * AS + j * 16 + l15] = f2b(sc[j][r]);
    }

    // O += P V   (P: LDS round-trip C-layout -> A-layout; per-wave region, same-wave order)
    #pragma unroll
    for (int j2 = 0; j2 < 4; ++j2){
      #pragma unroll
      for (int kk = 0; kk < 2; ++kk){
        bf16x8 afr = *(const bf16x8*)&pw[l15 * AS + kk * 32 + quad * 8];
        bf16x8 bfr = *(const bf16x8*)&vls[(j2 * 16 + l15) * AS + kk * 32 + quad * 8];
        o[j2] = __builtin_amdgcn_mfma_f32_16x16x32_bf16(afr, bfr, o[j2], 0, 0, 0);
      }
    }
  }

  #pragma unroll
  for (int j2 = 0; j2 < 4; ++j2){
    #pragma unroll
    for (int r = 0; r < 4; ++r){
      const int qrow = q0 + wv * 16 + quad * 4 + r;
      const int d = j2 * 16 + l15;
      Og[(size_t)qrow * 1024u + d] = f2b(o[j2][r] / l_r[r]);
    }
  }
}

extern "C" void kernel_launch(void* const* d_in, const int* in_sizes, int n_in,
                              void* d_out, int out_size, void* d_ws, size_t ws_size,
                              hipStream_t stream){
  (void)in_sizes; (void)n_in; (void)out_size; (void)ws_size;
  const float* x   = (const float*)d_in[0];
  const float* Wq  = (const float*)d_in[1];
  const float* bq  = (const float*)d_in[2];
  const float* Wk  = (const float*)d_in[3];
  const float* bk  = (const float*)d_in[4];
  const float* Wv  = (const float*)d_in[5];
  const float* bv  = (const float*)d_in[6];
  const float* Wo  = (const float*)d_in[7];
  const float* bo  = (const float*)d_in[8];
  const float* lng = (const float*)d_in[9];
  const float* lnb = (const float*)d_in[10];
  float* out = (float*)d_out;

  // Workspace (bf16 intermediates): 3 x 16MB activations + 8MB weights = 56MB.
  //   ws0: h (LN out, bf16) -> reused as vt after V projection
  //   ws1: q                -> attention output written IN PLACE over q
  //   ws2: k
  //   wsw: Wq|Wk|Wv|Wo bf16 copies (4 x 1M elems)
  //   d_out (fp32, 33.5MB): first 16.8MB used as bf16 scratch for v,
  //                         consumed by transpose before final GEMM writes it.
  const size_t TE = (size_t)8192 * 1024;  // elems per (T,H) activation
  u16* ws0 = (u16*)d_ws;
  u16* ws1 = ws0 + TE;
  u16* ws2 = ws1 + TE;
  u16* wsw = ws2 + TE;
  u16* wqb = wsw;
  u16* wkb = wsw + (size_t)1024 * 1024;
  u16* wvb = wsw + (size_t)2 * 1024 * 1024;
  u16* wob = wsw + (size_t)3 * 1024 * 1024;
  u16* v   = (u16*)d_out;   // bf16 scratch inside d_out

  cvt_w<<<dim3(1024, 4), 256, 0, stream>>>(Wq, Wk, Wv, Wo, wsw);
  ln_kernel<<<dim3(8192), 256, 0, stream>>>(x, lng, lnb, ws0);
  gemm_bt<0><<<dim3(64, 8), 256, 0, stream>>>(ws0, wqb, bq, nullptr, (void*)ws1, 8192, 1024, 1024);
  gemm_bt<0><<<dim3(64, 8), 256, 0, stream>>>(ws0, wkb, bk, nullptr, (void*)ws2, 8192, 1024, 1024);
  gemm_bt<0><<<dim3(64, 8), 256, 0, stream>>>(ws0, wvb, bv, nullptr, (void*)v,   8192, 1024, 1024);
  transpose_v<<<dim3(2048), 256, 0, stream>>>(v, ws0);
  attn_kernel<<<dim3(2048), 256, 0, stream>>>(ws1, ws2, ws0, ws1);
  gemm_bt<1><<<dim3(64, 8), 256, 0, stream>>>(ws1, wob, bo, x, (void*)out, 8192, 1024, 1024);
}

// Round 4
// 408.045 us; speedup vs baseline: 1.1481x; 1.1481x over previous
//
#include <hip/hip_runtime.h>

typedef unsigned short u16;
typedef unsigned int   u32;
using bf16x8 = __attribute__((ext_vector_type(8))) __bf16;
using f32x4  = __attribute__((ext_vector_type(4))) float;

__device__ __forceinline__ float b2f(u16 u){ union { float f; u32 i; } v; v.i = ((u32)u) << 16; return v.f; }
__device__ __forceinline__ u16 f2b(float f){
  union { float f; u32 i; } v; v.f = f;
  u32 r = v.i + 0x7FFFu + ((v.i >> 16) & 1u);
  return (u16)(r >> 16);
}
// pack bf16(trunc) of a (low16) and b (high16) in one v_perm_b32
__device__ __forceinline__ u32 pk_bf16_trunc(float a, float b){
  return __builtin_amdgcn_perm(__float_as_uint(b), __float_as_uint(a), 0x07060302u);
}

// ---------------------------------------------------------------- fp32 -> bf16 weight convert
__global__ __launch_bounds__(256) void cvt_w(const float* __restrict__ s0, const float* __restrict__ s1,
                                             const float* __restrict__ s2, const float* __restrict__ s3,
                                             u16* __restrict__ d){
  const float* srcs[4] = {s0, s1, s2, s3};
  const float* s = srcs[blockIdx.y];
  u16* dd = d + (size_t)blockIdx.y * (1024u * 1024u);
  const int i = (blockIdx.x * 256 + threadIdx.x) * 4;
  float4 v = *(const float4*)(s + i);
  uint2 o;
  o.x = (u32)f2b(v.x) | ((u32)f2b(v.y) << 16);
  o.y = (u32)f2b(v.z) | ((u32)f2b(v.w) << 16);
  *(uint2*)(dd + i) = o;
}

// ---------------------------------------------------------------- LayerNorm (fp32 in, bf16 out)
__global__ __launch_bounds__(256) void ln_kernel(const float* __restrict__ x, const float* __restrict__ g,
                                                 const float* __restrict__ be, u16* __restrict__ h){
  const int row = blockIdx.x, tid = threadIdx.x;
  const float* xr = x + (size_t)row * 1024u;
  float4 raw = *(const float4*)(xr + tid * 4);
  float s  = raw.x + raw.y + raw.z + raw.w;
  float sq = raw.x*raw.x + raw.y*raw.y + raw.z*raw.z + raw.w*raw.w;
  #pragma unroll
  for (int m = 1; m < 64; m <<= 1){ s += __shfl_xor(s, m); sq += __shfl_xor(sq, m); }
  __shared__ float ws[4], wq[4];
  if ((tid & 63) == 0){ ws[tid >> 6] = s; wq[tid >> 6] = sq; }
  __syncthreads();
  s  = ws[0] + ws[1] + ws[2] + ws[3];
  sq = wq[0] + wq[1] + wq[2] + wq[3];
  const float mu = s * (1.0f / 1024.0f);
  const float rstd = rsqrtf(sq * (1.0f / 1024.0f) - mu * mu + 1e-5f);
  float4 gg = *(const float4*)(g + tid * 4);
  float4 bb = *(const float4*)(be + tid * 4);
  float y0 = (raw.x - mu) * rstd * gg.x + bb.x;
  float y1 = (raw.y - mu) * rstd * gg.y + bb.y;
  float y2 = (raw.z - mu) * rstd * gg.z + bb.z;
  float y3 = (raw.w - mu) * rstd * gg.w + bb.w;
  uint2 outv;
  outv.x = (u32)f2b(y0) | ((u32)f2b(y1) << 16);
  outv.y = (u32)f2b(y2) | ((u32)f2b(y3) << 16);
  *(uint2*)(h + (size_t)row * 1024u + tid * 4) = outv;
}

// ---------------------------------------------------------------- GEMM: C = A * W^T + bias (+res)
// global_load_lds width-16 staging (m97 pattern), 128x128 tile, BK=32.
template<int F32OUT>
__global__ __launch_bounds__(256) void gemm_bt(const u16* __restrict__ A, const u16* __restrict__ W,
                                               const float* __restrict__ bias, const float* __restrict__ res,
                                               void* __restrict__ Cv, int M, int N, int K){
  __shared__ u16 lA[128 * 32];
  __shared__ u16 lB[128 * 32];
  const int tid = threadIdx.x;
  const int lane = tid & 63, wv = tid >> 6, l15 = lane & 15, quad = lane >> 4;
  const int wr = wv >> 1, wc = wv & 1;
  const int row0 = blockIdx.x * 128, col0 = blockIdx.y * 128;
  f32x4 acc[4][4] = {};
  const int nkt = K >> 5;
  for (int kt = 0; kt < nkt; ++kt){
    __syncthreads();
    #pragma unroll
    for (int jj = 0; jj < 2; ++jj){
      int idx = jj * 256 + tid;
      int r = idx >> 2, c = idx & 3;          // 128 rows x 4 chunks of 8 bf16
      __builtin_amdgcn_global_load_lds(
        (const __attribute__((address_space(1))) void*)(A + (size_t)(row0 + r) * K + (kt * 32 + c * 8)),
        (__attribute__((address_space(3))) void*)(&lA[idx * 8]), 16, 0, 0);
      __builtin_amdgcn_global_load_lds(
        (const __attribute__((address_space(1))) void*)(W + (size_t)(col0 + r) * K + (kt * 32 + c * 8)),
        (__attribute__((address_space(3))) void*)(&lB[idx * 8]), 16, 0, 0);
    }
    __syncthreads();
    bf16x8 af[4], bf[4];
    #pragma unroll
    for (int i = 0; i < 4; ++i) af[i] = *(const bf16x8*)&lA[(wr * 64 + i * 16 + l15) * 32 + quad * 8];
    #pragma unroll
    for (int j = 0; j < 4; ++j) bf[j] = *(const bf16x8*)&lB[(wc * 64 + j * 16 + l15) * 32 + quad * 8];
    #pragma unroll
    for (int i = 0; i < 4; ++i)
      #pragma unroll
      for (int j = 0; j < 4; ++j)
        acc[i][j] = __builtin_amdgcn_mfma_f32_16x16x32_bf16(af[i], bf[j], acc[i][j], 0, 0, 0);
  }
  #pragma unroll
  for (int i = 0; i < 4; ++i){
    const int grow = row0 + wr * 64 + i * 16 + quad * 4;
    #pragma unroll
    for (int j = 0; j < 4; ++j){
      const int gcol = col0 + wc * 64 + j * 16 + l15;
      const float bb = bias[gcol];
      #pragma unroll
      for (int r = 0; r < 4; ++r){
        size_t off = (size_t)(grow + r) * N + gcol;
        float v = acc[i][j][r] + bb;
        if (res) v += res[off];
        if (F32OUT) ((float*)Cv)[off] = v;
        else        ((u16*)Cv)[off] = f2b(v);
      }
    }
  }
}

// ---------------------------------------------------------------- V (b,s,h*64+d) -> Vt (b,h,d,s)  [bf16]
__global__ __launch_bounds__(256) void transpose_v(const u16* __restrict__ V, u16* __restrict__ Vt){
  __shared__ u16 t[64 * 66];
  const int bh = blockIdx.x >> 5, st = blockIdx.x & 31;
  const int b = bh >> 4, hh = bh & 15;
  const u16* Vg = V + ((size_t)b * 2048u + st * 64u) * 1024u + hh * 64;
  u16* Og = Vt + (size_t)bh * 64u * 2048u + st * 64u;
  #pragma unroll
  for (int i = 0; i < 16; ++i){
    int idx = i * 256 + threadIdx.x;
    int s = idx >> 6, d = idx & 63;
    t[s * 66 + d] = Vg[(size_t)s * 1024u + d];
  }
  __syncthreads();
  #pragma unroll
  for (int i = 0; i < 16; ++i){
    int idx = i * 256 + threadIdx.x;
    int d = idx >> 6, s = idx & 63;
    Og[(size_t)d * 2048u + s] = t[s * 66 + d];
  }
}

// ---------------------------------------------------------------- flash attention (bf16 in/out)
// S^T orientation: QK^T computed as K·Q^T so each lane owns ONE q-row (q_local = l15).
// Per-lane softmax: 15 in-lane ops + 2 shfls per reduction; P packed b64 writes.
// O may alias Q (each block touches only its own 64-row region, read-once-then-write).
#define AS 72
#define PS 72
__global__ __launch_bounds__(256) void attn_kernel(const u16* __restrict__ Q, const u16* __restrict__ K,
                                                   const u16* __restrict__ Vt, u16* __restrict__ O){
  __shared__ u16 kls[64 * AS];
  __shared__ u16 vls[64 * AS];
  __shared__ u16 pls[64 * PS];   // 4 waves x 16 q-rows
  const int tid = threadIdx.x;
  const int lane = tid & 63, wv = tid >> 6, l15 = lane & 15, quad = lane >> 4;
  const int bh = blockIdx.x >> 5, qt = blockIdx.x & 31;
  const int b = bh >> 4, hh = bh & 15;
  const int q0 = qt * 64;
  const u16* Qg = Q + ((size_t)b * 2048u) * 1024u + hh * 64;
  const u16* Kg = K + ((size_t)b * 2048u) * 1024u + hh * 64;
  const u16* Vg = Vt + (size_t)bh * 64u * 2048u;
  u16* Og = O + ((size_t)b * 2048u) * 1024u + hh * 64;

  // stage Q tile (reuses kls), pull per-wave frags (B-operand layout), pre-scale
  #pragma unroll
  for (int jj = 0; jj < 2; ++jj){
    int idx = jj * 256 + tid, r = idx >> 3, c = idx & 7;
    *(uint4*)&kls[r * AS + c * 8] = *(const uint4*)(Qg + (size_t)(q0 + r) * 1024u + c * 8);
  }
  __syncthreads();
  bf16x8 qf[2];
  const float QSCALE = 0.125f * 1.44269504f;   // fold 1/sqrt(64) and log2(e); exp->exp2 domain
  #pragma unroll
  for (int kk = 0; kk < 2; ++kk){
    qf[kk] = *(const bf16x8*)&kls[(wv * 16 + l15) * AS + kk * 32 + quad * 8];
    #pragma unroll
    for (int e = 0; e < 8; ++e) qf[kk][e] = (__bf16)((float)qf[kk][e] * QSCALE);
  }

  float m_run = -1.0e30f, l_run = 0.0f;
  f32x4 o[4] = {};
  u16* pw = &pls[wv * 16 * PS];

  for (int kt = 0; kt < 32; ++kt){
    __syncthreads();
    const int s0 = kt * 64;
    #pragma unroll
    for (int jj = 0; jj < 2; ++jj){
      int idx = jj * 256 + tid, r = idx >> 3, c = idx & 7;
      *(uint4*)&kls[r * AS + c * 8] = *(const uint4*)(Kg + (size_t)(s0 + r) * 1024u + c * 8);
      *(uint4*)&vls[r * AS + c * 8] = *(const uint4*)(Vg + (size_t)r * 2048u + s0 + c * 8);
    }
    __syncthreads();

    // S^T tile = K Q^T  (C layout: col=l15 -> q_local, row=16j+4quad+r -> kv)
    f32x4 sc[4];
    #pragma unroll
    for (int j = 0; j < 4; ++j){
      f32x4 a = {0.f, 0.f, 0.f, 0.f};
      #pragma unroll
      for (int kk = 0; kk < 2; ++kk){
        bf16x8 kfr = *(const bf16x8*)&kls[(j * 16 + l15) * AS + kk * 32 + quad * 8];
        a = __builtin_amdgcn_mfma_f32_16x16x32_bf16(kfr, qf[kk], a, 0, 0, 0);
      }
      sc[j] = a;
    }

    // per-lane online softmax for q_local = l15 (16 in-lane kv values, exp2 domain)
    float t = sc[0][0];
    #pragma unroll
    for (int j = 0; j < 4; ++j)
      #pragma unroll
      for (int r = 0; r < 4; ++r) t = fmaxf(t, sc[j][r]);
    t = fmaxf(t, __shfl_xor(t, 16));
    t = fmaxf(t, __shfl_xor(t, 32));
    const float mn = fmaxf(m_run, t);
    const float alpha = exp2f(m_run - mn);
    m_run = mn;
    float rs = 0.f;
    #pragma unroll
    for (int j = 0; j < 4; ++j)
      #pragma unroll
      for (int r = 0; r < 4; ++r){
        float p = exp2f(sc[j][r] - mn);
        sc[j][r] = p;
        rs += p;
      }
    rs += __shfl_xor(rs, 16);
    rs += __shfl_xor(rs, 32);
    l_run = l_run * alpha + rs;

    // rescale O by the alpha of its own row (held by lane l15 = quad*4+r)
    #pragma unroll
    for (int r = 0; r < 4; ++r){
      const float ar = __shfl(alpha, quad * 4 + r);
      #pragma unroll
      for (int j2 = 0; j2 < 4; ++j2) o[j2][r] *= ar;
    }

    // write P[q_local][kv] packed (r=0..3 kv-consecutive -> one b64 per j)
    #pragma unroll
    for (int j = 0; j < 4; ++j){
      uint2 pk;
      pk.x = pk_bf16_trunc(sc[j][0], sc[j][1]);
      pk.y = pk_bf16_trunc(sc[j][2], sc[j][3]);
      *(uint2*)&pw[l15 * PS + j * 16 + quad * 4] = pk;
    }

    // O += P V  (A-frag from pls, B-frag from vls; in-order DS pipe, same-wave)
    bf16x8 afr[2];
    afr[0] = *(const bf16x8*)&pw[l15 * PS + quad * 8];
    afr[1] = *(const bf16x8*)&pw[l15 * PS + 32 + quad * 8];
    #pragma unroll
    for (int j2 = 0; j2 < 4; ++j2){
      #pragma unroll
      for (int kk = 0; kk < 2; ++kk){
        bf16x8 bfr = *(const bf16x8*)&vls[(j2 * 16 + l15) * AS + kk * 32 + quad * 8];
        o[j2] = __builtin_amdgcn_mfma_f32_16x16x32_bf16(afr[kk], bfr, o[j2], 0, 0, 0);
      }
    }
  }

  float lr[4];
  #pragma unroll
  for (int r = 0; r < 4; ++r) lr[r] = 1.0f / __shfl(l_run, quad * 4 + r);
  #pragma unroll
  for (int j2 = 0; j2 < 4; ++j2){
    #pragma unroll
    for (int r = 0; r < 4; ++r){
      const int qrow = q0 + wv * 16 + quad * 4 + r;
      const int d = j2 * 16 + l15;
      Og[(size_t)qrow * 1024u + d] = f2b(o[j2][r] * lr[r]);
    }
  }
}

extern "C" void kernel_launch(void* const* d_in, const int* in_sizes, int n_in,
                              void* d_out, int out_size, void* d_ws, size_t ws_size,
                              hipStream_t stream){
  (void)in_sizes; (void)n_in; (void)out_size; (void)ws_size;
  const float* x   = (const float*)d_in[0];
  const float* Wq  = (const float*)d_in[1];
  const float* bq  = (const float*)d_in[2];
  const float* Wk  = (const float*)d_in[3];
  const float* bk  = (const float*)d_in[4];
  const float* Wv  = (const float*)d_in[5];
  const float* bv  = (const float*)d_in[6];
  const float* Wo  = (const float*)d_in[7];
  const float* bo  = (const float*)d_in[8];
  const float* lng = (const float*)d_in[9];
  const float* lnb = (const float*)d_in[10];
  float* out = (float*)d_out;

  const size_t TE = (size_t)8192 * 1024;
  u16* ws0 = (u16*)d_ws;          // h -> vt
  u16* ws1 = ws0 + TE;            // q -> attention out (in place)
  u16* ws2 = ws1 + TE;            // k
  u16* wsw = ws2 + TE;            // bf16 weights
  u16* wqb = wsw;
  u16* wkb = wsw + (size_t)1024 * 1024;
  u16* wvb = wsw + (size_t)2 * 1024 * 1024;
  u16* wob = wsw + (size_t)3 * 1024 * 1024;
  u16* v   = (u16*)d_out;         // bf16 scratch inside d_out

  cvt_w<<<dim3(1024, 4), 256, 0, stream>>>(Wq, Wk, Wv, Wo, wsw);
  ln_kernel<<<dim3(8192), 256, 0, stream>>>(x, lng, lnb, ws0);
  gemm_bt<0><<<dim3(64, 8), 256, 0, stream>>>(ws0, wqb, bq, nullptr, (void*)ws1, 8192, 1024, 1024);
  gemm_bt<0><<<dim3(64, 8), 256, 0, stream>>>(ws0, wkb, bk, nullptr, (void*)ws2, 8192, 1024, 1024);
  gemm_bt<0><<<dim3(64, 8), 256, 0, stream>>>(ws0, wvb, bv, nullptr, (void*)v,   8192, 1024, 1024);
  transpose_v<<<dim3(2048), 256, 0, stream>>>(v, ws0);
  attn_kernel<<<dim3(2048), 256, 0, stream>>>(ws1, ws2, ws0, ws1);
  gemm_bt<1><<<dim3(64, 8), 256, 0, stream>>>(ws1, wob, bo, x, (void*)out, 8192, 1024, 1024);
}